// Round 6
// baseline (155.466 us; speedup 1.0000x reference)
//
#include <hip/hip_runtime.h>

// Lorenz96 RK4, fp32 — branchless persistent ping-pong (exact-divide path):
//   BATCH*10 float4s = 5,242,880 = 10 x 524,288 threads (2048 blocks x 256,
//   8 blocks/CU). Every thread does EXACTLY 10 chunks -> all bounds checks
//   are dead and removed: the loop body is straight-line, uniform control
//   flow. That is the condition under which hipcc emits counted
//   s_waitcnt vmcnt(N) instead of draining vmcnt(0) at exec-mask branch
//   boundaries (rounds 3/4 showed zero overlap from source-level prefetch:
//   VALUBusy 42% == HBM 40% == duty cycle of a drain-serialized loop).
//   With the ping-pong counted, slot B's 4 loads stay in flight across
//   slot A's ~350-cycle compute.
//   Redundant-halo compute (window [p-8,p+7] = 4 aligned float4s, cols
//   c-2,c-1,c,c+1 mod 10): no cross-lane ops, no LDS, no barriers.
//   Derivative written as fmaf(a-b, c, F-d): 3 VALU/element guaranteed.
//   Stores are nontemporal: output is never re-read; don't evict the
//   L3-resident input.
//   (Round-5 submission of this source hit "container failed twice" —
//   infra flake, kernel re-audited for OOB/hang: none. Resubmitting.)

#define FORCE 8.0f

typedef float f32x4 __attribute__((ext_vector_type(4)));

__device__ __forceinline__ void nt_store(float4* p, const float4& v) {
    __builtin_nontemporal_store(*(const f32x4*)&v, (f32x4*)p);
}

__device__ __forceinline__ float4 rk4_chunk(const float4 vm2, const float4 vm1,
                                            const float4 v0,  const float4 vp1,
                                            const float dt,   const float hdt)
{
    float xa[16];
    xa[0]=vm2.x;  xa[1]=vm2.y;  xa[2]=vm2.z;  xa[3]=vm2.w;
    xa[4]=vm1.x;  xa[5]=vm1.y;  xa[6]=vm1.z;  xa[7]=vm1.w;
    xa[8]=v0.x;   xa[9]=v0.y;   xa[10]=v0.z;  xa[11]=v0.w;
    xa[12]=vp1.x; xa[13]=vp1.y; xa[14]=vp1.z; xa[15]=vp1.w;

    // d[i] = (x[i+1]-x[i-2])*x[i-1] - x[i] + F; window-relative:
    //   D[i] = fmaf(S[i+3]-S[i], S[i+1], F - S[i+2])   (window shrinks by 3)
    float k1[13], y1[13];
#pragma unroll
    for (int i = 0; i < 13; ++i)
        k1[i] = fmaf(xa[i+3] - xa[i], xa[i+1], FORCE - xa[i+2]);
#pragma unroll
    for (int i = 0; i < 13; ++i)
        y1[i] = fmaf(hdt, k1[i], xa[i+2]);

    float k2[10], y2[10];
#pragma unroll
    for (int i = 0; i < 10; ++i)
        k2[i] = fmaf(y1[i+3] - y1[i], y1[i+1], FORCE - y1[i+2]);
#pragma unroll
    for (int i = 0; i < 10; ++i)
        y2[i] = fmaf(hdt, k2[i], xa[i+4]);

    float k3[7], y3[7];
#pragma unroll
    for (int i = 0; i < 7; ++i)
        k3[i] = fmaf(y2[i+3] - y2[i], y2[i+1], FORCE - y2[i+2]);
#pragma unroll
    for (int i = 0; i < 7; ++i)
        y3[i] = fmaf(dt, k3[i], xa[i+6]);

    float k4[4];
#pragma unroll
    for (int i = 0; i < 4; ++i)
        k4[i] = fmaf(y3[i+3] - y3[i], y3[i+1], FORCE - y3[i+2]);

    const float sc = dt * (1.0f / 6.0f);
    float4 r;
    float t0 = k1[6] + k4[0]; t0 = fmaf(2.0f, k2[4], t0); t0 = fmaf(2.0f, k3[2], t0);
    float t1 = k1[7] + k4[1]; t1 = fmaf(2.0f, k2[5], t1); t1 = fmaf(2.0f, k3[3], t1);
    float t2 = k1[8] + k4[2]; t2 = fmaf(2.0f, k2[6], t2); t2 = fmaf(2.0f, k3[4], t2);
    float t3 = k1[9] + k4[3]; t3 = fmaf(2.0f, k2[7], t3); t3 = fmaf(2.0f, k3[5], t3);
    r.x = fmaf(sc, t0, xa[8]);
    r.y = fmaf(sc, t1, xa[9]);
    r.z = fmaf(sc, t2, xa[10]);
    r.w = fmaf(sc, t3, xa[11]);
    return r;
}

// 4 stencil loads for chunk at float4 index F, column C = F mod 10
#define LOADS(F, C, A, B, Cc, D)                                             \
    {                                                                        \
        const int om2 = ((C) >= 2) ? -2 : 8;                                 \
        const int om1 = ((C) >= 1) ? -1 : 9;                                 \
        const int op1 = ((C) <= 8) ?  1 : -9;                                \
        A  = x0[(F) + om2];                                                  \
        B  = x0[(F) + om1];                                                  \
        Cc = x0[(F)];                                                        \
        D  = x0[(F) + op1];                                                  \
    }

// ---------- exact-divide path: nf4 == stride * (2*npair + 2), branchless ----
__global__ __launch_bounds__(256)
void lorenz96_rk4_exact(const float4* __restrict__ x0,
                        const float* __restrict__ dt_p,
                        float4* __restrict__ out,
                        unsigned stride,   // total threads in grid
                        int cstep,         // stride % 10
                        int cstep2,        // (2*stride) % 10
                        int npair)         // (niter-2)/2 steady iterations
{
    const unsigned tid = blockIdx.x * blockDim.x + threadIdx.x;
    const float dt  = dt_p[0];
    const float hdt = 0.5f * dt;

    unsigned f0 = tid;
    int      c0 = (int)(tid % 10u);
    unsigned f1 = tid + stride;
    int      c1 = c0 + cstep; if (c1 >= 10) c1 -= 10;

    float4 A0, B0, C0, D0;
    float4 A1, B1, C1, D1;
    LOADS(f0, c0, A0, B0, C0, D0)
    LOADS(f1, c1, A1, B1, C1, D1)

    for (int i = 0; i < npair; ++i) {
        // compute+store slot 0 (its loads were issued one full phase ago),
        // then immediately refill slot 0 for iteration i+2
        float4 r0 = rk4_chunk(A0, B0, C0, D0, dt, hdt);
        nt_store(&out[f0], r0);
        f0 += 2u * stride;
        c0 += cstep2; if (c0 >= 10) c0 -= 10;
        LOADS(f0, c0, A0, B0, C0, D0)

        float4 r1 = rk4_chunk(A1, B1, C1, D1, dt, hdt);
        nt_store(&out[f1], r1);
        f1 += 2u * stride;
        c1 += cstep2; if (c1 >= 10) c1 -= 10;
        LOADS(f1, c1, A1, B1, C1, D1)
    }
    // epilogue: two final chunks, already loaded
    float4 r0 = rk4_chunk(A0, B0, C0, D0, dt, hdt);
    nt_store(&out[f0], r0);
    float4 r1 = rk4_chunk(A1, B1, C1, D1, dt, hdt);
    nt_store(&out[f1], r1);
}

// ---------- generic fallback (branchy, any size) ----------------------------
__global__ __launch_bounds__(256)
void lorenz96_rk4_persist(const float4* __restrict__ x0,
                          const float* __restrict__ dt_p,
                          float4* __restrict__ out,
                          unsigned nf4, unsigned stride, int cstep, int niter)
{
    const unsigned tid = blockIdx.x * blockDim.x + threadIdx.x;
    const float dt  = dt_p[0];
    const float hdt = 0.5f * dt;

    float4 A0, B0, C0, D0;
    float4 A1, B1, C1, D1;

    unsigned f0 = tid;
    int      c0 = (int)(f0 % 10u);
    bool   act0 = (f0 < nf4);
    if (act0) LOADS(f0, c0, A0, B0, C0, D0)

    unsigned f1 = f0 + stride;
    int      c1 = c0 + cstep; if (c1 >= 10) c1 -= 10;

    for (int it = 0; it < niter; it += 2) {
        const bool act1 = (f1 < nf4);
        if (act1) LOADS(f1, c1, A1, B1, C1, D1)
        if (act0) out[f0] = rk4_chunk(A0, B0, C0, D0, dt, hdt);

        f0 = f1 + stride;
        c0 = c1 + cstep; if (c0 >= 10) c0 -= 10;
        act0 = (f0 < nf4);

        if (act0) LOADS(f0, c0, A0, B0, C0, D0)
        if (act1) out[f1] = rk4_chunk(A1, B1, C1, D1, dt, hdt);

        f1 = f0 + stride;
        c1 = c0 + cstep; if (c1 >= 10) c1 -= 10;
    }
}

extern "C" void kernel_launch(void* const* d_in, const int* in_sizes, int n_in,
                              void* d_out, int out_size, void* d_ws, size_t ws_size,
                              hipStream_t stream) {
    const float4* x0 = (const float4*)d_in[0];
    // d_in[1] = t (unused; autonomous system)
    const float* dt = (const float*)d_in[2];
    float4* out = (float4*)d_out;

    const unsigned nf4 = (unsigned)((long)in_sizes[0] / 4);  // batch*10 float4s
    const int block = 256;
    const unsigned grid = 2048;                  // 8 blocks/CU, persistent
    const unsigned stride = grid * block;        // 524288 threads
    const int cstep  = (int)(stride % 10u);
    const int cstep2 = (int)((2ull * stride) % 10u);

    if (nf4 % stride == 0 && (nf4 / stride) >= 4 && (nf4 / stride) % 2 == 0) {
        const int niter = (int)(nf4 / stride);   // == 10 for this problem
        const int npair = (niter - 2) / 2;
        lorenz96_rk4_exact<<<dim3(grid), dim3(block), 0, stream>>>(
            x0, dt, out, stride, cstep, cstep2, npair);
    } else {
        int niter = (int)((nf4 + stride - 1) / stride);
        if (niter & 1) ++niter;
        lorenz96_rk4_persist<<<dim3(grid), dim3(block), 0, stream>>>(
            x0, dt, out, nf4, stride, cstep, niter);
    }
}

// Round 7
// 147.160 us; speedup vs baseline: 1.0564x; 1.0564x over previous
//
#include <hip/hip_runtime.h>

// Lorenz96 RK4, fp32 — LDS-shared stencil, minimal global requests:
//   Rounds 0-6 invariance (~50us across 6 structures, no pipe >43%) killed
//   the scheduling theories; surviving model is per-CU L1/TCP request-queue
//   congestion from 4x read amplification (4 wave64 dwordx4 loads/chunk,
//   16 line-requests each, dozens outstanding -> effective load latency in
//   the thousands of cycles, all waves stalled at once).
//   This kernel issues the MINIMUM: 1 global load + 1 global store per
//   float4. Halo comes from LDS: block = 320 threads = exactly 32 rows
//   (320 % 10 == 0, nf4 = 16384 * 320 exactly), so every row is
//   block-local and the column c = tid % 10 needs no global index math.
//   Per thread: load own float4 -> LDS(+reg), barrier, 3x ds_read_b128
//   (cols c-2, c-1, c+1 mod 10 of own row), redundant-halo RK4 in
//   registers (window [p-8,p+7] = the 4 float4s), nontemporal store.
//   No cross-stage LDS traffic, one barrier total.

#define FORCE 8.0f

typedef float f32x4 __attribute__((ext_vector_type(4)));

__device__ __forceinline__ void nt_store(float4* p, const float4& v) {
    __builtin_nontemporal_store(*(const f32x4*)&v, (f32x4*)p);
}

__device__ __forceinline__ float4 rk4_chunk(const float4 vm2, const float4 vm1,
                                            const float4 v0,  const float4 vp1,
                                            const float dt,   const float hdt)
{
    float xa[16];
    xa[0]=vm2.x;  xa[1]=vm2.y;  xa[2]=vm2.z;  xa[3]=vm2.w;
    xa[4]=vm1.x;  xa[5]=vm1.y;  xa[6]=vm1.z;  xa[7]=vm1.w;
    xa[8]=v0.x;   xa[9]=v0.y;   xa[10]=v0.z;  xa[11]=v0.w;
    xa[12]=vp1.x; xa[13]=vp1.y; xa[14]=vp1.z; xa[15]=vp1.w;

    // d[i] = (x[i+1]-x[i-2])*x[i-1] - x[i] + F; window-relative:
    //   D[i] = fmaf(S[i+3]-S[i], S[i+1], F - S[i+2])  (window shrinks by 3)
    float k1[13], y1[13];
#pragma unroll
    for (int i = 0; i < 13; ++i)
        k1[i] = fmaf(xa[i+3] - xa[i], xa[i+1], FORCE - xa[i+2]);
#pragma unroll
    for (int i = 0; i < 13; ++i)
        y1[i] = fmaf(hdt, k1[i], xa[i+2]);

    float k2[10], y2[10];
#pragma unroll
    for (int i = 0; i < 10; ++i)
        k2[i] = fmaf(y1[i+3] - y1[i], y1[i+1], FORCE - y1[i+2]);
#pragma unroll
    for (int i = 0; i < 10; ++i)
        y2[i] = fmaf(hdt, k2[i], xa[i+4]);

    float k3[7], y3[7];
#pragma unroll
    for (int i = 0; i < 7; ++i)
        k3[i] = fmaf(y2[i+3] - y2[i], y2[i+1], FORCE - y2[i+2]);
#pragma unroll
    for (int i = 0; i < 7; ++i)
        y3[i] = fmaf(dt, k3[i], xa[i+6]);

    float k4[4];
#pragma unroll
    for (int i = 0; i < 4; ++i)
        k4[i] = fmaf(y3[i+3] - y3[i], y3[i+1], FORCE - y3[i+2]);

    const float sc = dt * (1.0f / 6.0f);
    float4 r;
    float t0 = k1[6] + k4[0]; t0 = fmaf(2.0f, k2[4], t0); t0 = fmaf(2.0f, k3[2], t0);
    float t1 = k1[7] + k4[1]; t1 = fmaf(2.0f, k2[5], t1); t1 = fmaf(2.0f, k3[3], t1);
    float t2 = k1[8] + k4[2]; t2 = fmaf(2.0f, k2[6], t2); t2 = fmaf(2.0f, k3[4], t2);
    float t3 = k1[9] + k4[3]; t3 = fmaf(2.0f, k2[7], t3); t3 = fmaf(2.0f, k3[5], t3);
    r.x = fmaf(sc, t0, xa[8]);
    r.y = fmaf(sc, t1, xa[9]);
    r.z = fmaf(sc, t2, xa[10]);
    r.w = fmaf(sc, t3, xa[11]);
    return r;
}

// ---------- LDS path: requires nf4 % 320 == 0 (holds: 5,242,880 = 16384*320)
__global__ __launch_bounds__(320)
void lorenz96_rk4_lds(const float4* __restrict__ x0,
                      const float* __restrict__ dt_p,
                      float4* __restrict__ out)
{
    __shared__ float4 tile[320];            // 5 KB: 32 complete rows

    const unsigned tid = threadIdx.x;
    const unsigned f   = blockIdx.x * 320u + tid;

    const float4 own = x0[f];               // the ONLY global load
    tile[tid] = own;

    const float dt  = dt_p[0];
    const float hdt = 0.5f * dt;

    // column within row: blockIdx*320 ≡ 0 (mod 10) -> c depends on tid only
    const unsigned c   = tid % 10u;
    const unsigned rb  = tid - c;           // row base (local float4 index)
    const unsigned im2 = rb + ((c >= 2u) ? c - 2u : c + 8u);
    const unsigned im1 = rb + ((c >= 1u) ? c - 1u : c + 9u);
    const unsigned ip1 = rb + ((c <= 8u) ? c + 1u : c - 9u);

    __syncthreads();

    const float4 vm2 = tile[im2];
    const float4 vm1 = tile[im1];
    const float4 vp1 = tile[ip1];

    const float4 r = rk4_chunk(vm2, vm1, own, vp1, dt, hdt);
    nt_store(&out[f], r);
}

// ---------- generic fallback (any size): round-2 one-shot halo kernel ------
__global__ __launch_bounds__(256)
void lorenz96_rk4_halo(const float4* __restrict__ x0,
                       const float* __restrict__ dt_p,
                       float4* __restrict__ out,
                       long nf4)
{
    const long f = (long)blockIdx.x * blockDim.x + threadIdx.x;
    if (f >= nf4) return;
    const long r  = f / 10;
    const int  c  = (int)(f - r * 10);
    const long rb = r * 10;
    const int cm2 = (c >= 2) ? c - 2 : c + 8;
    const int cm1 = (c >= 1) ? c - 1 : c + 9;
    const int cp1 = (c <= 8) ? c + 1 : c - 9;

    const float4 vm2 = x0[rb + cm2];
    const float4 vm1 = x0[rb + cm1];
    const float4 v0  = x0[rb + c  ];
    const float4 vp1 = x0[rb + cp1];

    const float dt  = dt_p[0];
    const float hdt = 0.5f * dt;
    const float4 res = rk4_chunk(vm2, vm1, v0, vp1, dt, hdt);
    nt_store(&out[f], res);
}

extern "C" void kernel_launch(void* const* d_in, const int* in_sizes, int n_in,
                              void* d_out, int out_size, void* d_ws, size_t ws_size,
                              hipStream_t stream) {
    const float4* x0 = (const float4*)d_in[0];
    // d_in[1] = t (unused; autonomous system)
    const float* dt = (const float*)d_in[2];
    float4* out = (float4*)d_out;

    const long nf4 = (long)in_sizes[0] / 4;        // batch*10 float4s

    if (nf4 % 320 == 0) {
        const unsigned grid = (unsigned)(nf4 / 320);
        lorenz96_rk4_lds<<<dim3(grid), dim3(320), 0, stream>>>(x0, dt, out);
    } else {
        const int block = 256;
        const long grid = (nf4 + block - 1) / block;
        lorenz96_rk4_halo<<<dim3((unsigned)grid), dim3(block), 0, stream>>>(
            x0, dt, out, nf4);
    }
}